// Round 9
// baseline (276.791 us; speedup 1.0000x reference)
//
#include <hip/hip_runtime.h>
#include <hip/hip_bf16.h>

#define BB 16
#define NN 4096
#define SS 1024
#define DD 256
#define O1C 256
#define O2C 128
#define NT 128   // n-tile of fused kernel

typedef __attribute__((ext_vector_type(8))) short bf16x8;
typedef __attribute__((ext_vector_type(4))) float f32x4;
typedef __attribute__((ext_vector_type(2))) unsigned int u32x2;

static __device__ __forceinline__ unsigned short f2bf(float f) {
    union { float f; unsigned u; } v; v.f = f;
    unsigned r = (v.u + 0x7fffu + ((v.u >> 16) & 1u)) >> 16;
    return (unsigned short)r;
}

// ---------------------------------------------------------------------------
// Prep: W fp32 -> bf16, fold BN into scale/shift.  grid 384 x 256.
// ---------------------------------------------------------------------------
__global__ __launch_bounds__(256) void prep_kernel(
    const float* __restrict__ W1, const float* __restrict__ W2,
    const float* __restrict__ b1, const float* __restrict__ g1,
    const float* __restrict__ be1, const float* __restrict__ m1,
    const float* __restrict__ v1,
    const float* __restrict__ b2, const float* __restrict__ g2,
    const float* __restrict__ be2, const float* __restrict__ m2,
    const float* __restrict__ v2,
    unsigned short* __restrict__ W1b, unsigned short* __restrict__ W2b,
    float* __restrict__ sc1, float* __restrict__ sh1,
    float* __restrict__ sc2, float* __restrict__ sh2)
{
    int t = blockIdx.x * 256 + threadIdx.x;
    if (t < O1C * DD) W1b[t] = f2bf(W1[t]);
    int t2 = t - O1C * DD;
    if (t2 >= 0 && t2 < O2C * O1C) W2b[t2] = f2bf(W2[t2]);
    if (t < O1C) {
        float s = g1[t] / sqrtf(v1[t] + 1e-5f);
        sc1[t] = s;
        sh1[t] = (b1[t] - m1[t]) * s + be1[t];
    }
    if (t2 >= 0 && t2 < O2C) {
        float s = g2[t2] / sqrtf(v2[t2] + 1e-5f);
        sc2[t2] = s;
        sh2[t2] = (b2[t2] - m2[t2]) * s + be2[t2];
    }
}

// ---------------------------------------------------------------------------
// Transpose points2 [B,D,S] -> p2t [B,S,D] fp32.  64x64 tiles, padded LDS.
// grid: BB * 4 * 16 = 1024 blocks x 256 threads.
// ---------------------------------------------------------------------------
__global__ __launch_bounds__(256) void transpose_kernel(
    const float* __restrict__ p2,   // [B,D,S]
    float* __restrict__ p2t)        // [B,S,D]
{
    __shared__ float tile[64][65];
    const int b  = blockIdx.x >> 6;
    const int ct = (blockIdx.x >> 4) & 3;   // c-tile 0..3
    const int st = blockIdx.x & 15;         // s-tile 0..15
    const int c0 = ct * 64, s0 = st * 64;
    const int cl = threadIdx.x >> 6;        // 0..3
    const int sl = threadIdx.x & 63;

    const float* src = p2 + ((size_t)b * DD + c0) * SS + s0;
    #pragma unroll
    for (int r = 0; r < 16; ++r) {
        const int c = r * 4 + cl;
        tile[c][sl] = src[(size_t)c * SS + sl];
    }
    __syncthreads();
    float* dst = p2t + ((size_t)b * SS + s0) * DD + c0;
    #pragma unroll
    for (int r = 0; r < 16; ++r) {
        const int s = r * 4 + cl;
        dst[(size_t)s * DD + sl] = tile[sl][s];
    }
}

// ---------------------------------------------------------------------------
// knn3: 8 threads per point, each scans S/8 = 128, stable LDS merge.
// grid: BB * (NN/64) = 1024 blocks x 512 threads (32 waves/CU).
// ---------------------------------------------------------------------------
__global__ __launch_bounds__(512) void knn3_kernel(
    const float* __restrict__ xyz1,   // [B,3,N]
    const float* __restrict__ xyz2,   // [B,3,S]
    int* __restrict__ idx_out,        // [B,N,3]
    float* __restrict__ w_out)        // [B,N,3]
{
    __shared__ float4 q[SS];          // 16 KB
    __shared__ float  cd[512][3];     // 6 KB
    __shared__ int    ci[512][3];     // 6 KB

    const int b    = blockIdx.x >> 6;     // 64 tiles per batch
    const int tile = blockIdx.x & 63;
    const int p    = threadIdx.x & 63;
    const int seg  = threadIdx.x >> 6;    // 0..7: which eighth of S
    const int n    = tile * 64 + p;

    const float* x2 = xyz2 + (size_t)b * 3 * SS;
    for (int s = threadIdx.x; s < SS; s += 512) {
        float xx = x2[s], yy = x2[SS + s], zz = x2[2 * SS + s];
        q[s] = make_float4(xx, yy, zz, xx * xx + yy * yy + zz * zz);
    }
    __syncthreads();

    const float* x1 = xyz1 + (size_t)b * 3 * NN;
    const float px = x1[n], py = x1[NN + n], pz = x1[2 * NN + n];
    const float pn = px * px + py * py + pz * pz;

    const float FINF = 3.402823466e+38f;
    float d0 = FINF, d1 = FINF, d2 = FINF;
    int   i0 = 0,    i1 = 0,    i2 = 0;

    const int s0 = seg * (SS / 8);
    #pragma unroll 4
    for (int s = s0; s < s0 + SS / 8; ++s) {
        float4 v = q[s];
        float d = pn + v.w - 2.0f * (px * v.x + py * v.y + pz * v.z);
        if (d < d2) {
            if (d < d1) {
                if (d < d0) { d2 = d1; i2 = i1; d1 = d0; i1 = i0; d0 = d; i0 = s; }
                else        { d2 = d1; i2 = i1; d1 = d;  i1 = s; }
            } else          { d2 = d;  i2 = s; }
        }
    }
    cd[threadIdx.x][0] = d0; cd[threadIdx.x][1] = d1; cd[threadIdx.x][2] = d2;
    ci[threadIdx.x][0] = i0; ci[threadIdx.x][1] = i1; ci[threadIdx.x][2] = i2;
    __syncthreads();

    if (threadIdx.x < 64) {
        float m0 = cd[p][0], m1v = cd[p][1], m2v = cd[p][2];
        int   j0 = ci[p][0], j1 = ci[p][1], j2 = ci[p][2];
        #pragma unroll
        for (int qq = 1; qq < 8; ++qq) {
            const int t = qq * 64 + p;
            #pragma unroll
            for (int c = 0; c < 3; ++c) {
                float d = cd[t][c]; int i = ci[t][c];
                // strict < keeps earliest index on ties (top_k stability);
                // segments merged in ascending-s order
                if (d < m2v) {
                    if (d < m1v) {
                        if (d < m0) { m2v = m1v; j2 = j1; m1v = m0; j1 = j0; m0 = d; j0 = i; }
                        else        { m2v = m1v; j2 = j1; m1v = d;  j1 = i; }
                    } else          { m2v = d;  j2 = i; }
                }
            }
        }
        float r0 = 1.0f / (m0 + 1e-8f);
        float r1 = 1.0f / (m1v + 1e-8f);
        float r2 = 1.0f / (m2v + 1e-8f);
        float rs = 1.0f / (r0 + r1 + r2);
        size_t base = ((size_t)b * NN + n) * 3;
        idx_out[base + 0] = j0;
        idx_out[base + 1] = j1;
        idx_out[base + 2] = j2;
        w_out[base + 0] = r0 * rs;
        w_out[base + 1] = r1 * rs;
        w_out[base + 2] = r2 * rs;
    }
}

// ---------------------------------------------------------------------------
// Fused interp + MFMA MLP.  grid: BB*(NN/NT) = 512 blocks x 512 threads.
// Staging gathers COALESCED full-D rows from p2t [B,S,D]:
//   wave w owns points w*16..w*16+15; per point the 64 lanes read the 3
//   neighbor rows as float4 (lane l -> channels 4l..4l+3), add points1
//   column loads (L1-line reuse across the wave's 16 consecutive n),
//   pack bf16 and write one contiguous swizzled 512B LDS row.
// GEMM1/epi1/GEMM2 unchanged (validated, absmax 0.031).
// ---------------------------------------------------------------------------
__global__ __launch_bounds__(512) void fused_mfma_kernel(
    const float* __restrict__ points1,  // [B,D,N]
    const float* __restrict__ p2t,      // [B,S,D] fp32
    const int*   __restrict__ idx_in,   // [B,N,3]
    const float* __restrict__ w_in,     // [B,N,3]
    const unsigned short* __restrict__ W1b,  // [O1,D] bf16
    const unsigned short* __restrict__ W2b,  // [O2,O1] bf16
    const float* __restrict__ sc1, const float* __restrict__ sh1,
    const float* __restrict__ sc2, const float* __restrict__ sh2,
    float* __restrict__ out)            // [B,O2,N]
{
    __shared__ unsigned short T[NT * DD];   // 64 KB

    const int blk  = blockIdx.x;
    const int b    = blk >> 5;            // 32 tiles per batch
    const int n0   = (blk & 31) * NT;
    const int tid  = threadIdx.x;
    const int lane = tid & 63;
    const int w    = tid >> 6;            // wave 0..7

    // ---------------- stage X^T[p][c] via coalesced row gather ----------------
    {
        const float* p2tb = p2t + (size_t)b * SS * DD;
        const float* p1b  = points1 + (size_t)b * DD * NN;
        #pragma unroll 2
        for (int pp = 0; pp < 16; ++pp) {
            const int p = w * 16 + pp;
            const int n = n0 + p;
            const size_t ibase = ((size_t)b * NN + n) * 3;
            const int   gi0 = idx_in[ibase + 0];
            const int   gi1 = idx_in[ibase + 1];
            const int   gi2 = idx_in[ibase + 2];
            const float gw0 = w_in[ibase + 0];
            const float gw1 = w_in[ibase + 1];
            const float gw2 = w_in[ibase + 2];
            const float4 r0 = *reinterpret_cast<const float4*>(p2tb + (size_t)gi0 * DD + 4 * lane);
            const float4 r1 = *reinterpret_cast<const float4*>(p2tb + (size_t)gi1 * DD + 4 * lane);
            const float4 r2 = *reinterpret_cast<const float4*>(p2tb + (size_t)gi2 * DD + 4 * lane);
            const float x0 = p1b[(size_t)(4 * lane + 0) * NN + n] + gw0 * r0.x + gw1 * r1.x + gw2 * r2.x;
            const float x1 = p1b[(size_t)(4 * lane + 1) * NN + n] + gw0 * r0.y + gw1 * r1.y + gw2 * r2.y;
            const float x2 = p1b[(size_t)(4 * lane + 2) * NN + n] + gw0 * r0.z + gw1 * r1.z + gw2 * r2.z;
            const float x3 = p1b[(size_t)(4 * lane + 3) * NN + n] + gw0 * r0.w + gw1 * r1.w + gw2 * r2.w;
            u32x2 pk;
            pk[0] = (unsigned)f2bf(x0) | ((unsigned)f2bf(x1) << 16);
            pk[1] = (unsigned)f2bf(x2) | ((unsigned)f2bf(x3) << 16);
            const int byteoff = p * 512 + ((8 * lane) ^ ((p & 7) << 4));
            *reinterpret_cast<u32x2*>(reinterpret_cast<char*>(T) + byteoff) = pk;
        }
    }
    __syncthreads();

    const int r16 = lane & 15;
    const int kg  = lane >> 4;
    const int wo  = w >> 1;               // 0..3
    const int wn  = w & 1;                // 0..1

    // ---------------- GEMM1: [256 o] x [k=256] x [128 n] ----------------
    f32x4 acc[4][4] = {};
    for (int ks = 0; ks < 8; ++ks) {
        const int kk = ks * 32;
        bf16x8 a[4], bf[4];
        #pragma unroll
        for (int m = 0; m < 4; ++m) {
            const int o = wo * 64 + m * 16 + r16;
            a[m] = *reinterpret_cast<const bf16x8*>(W1b + (size_t)o * DD + kk + kg * 8);
        }
        #pragma unroll
        for (int j = 0; j < 4; ++j) {
            const int nn = wn * 64 + j * 16 + r16;
            const int byteoff = nn * 512 + (((kk + kg * 8) * 2) ^ ((nn & 7) << 4));
            bf[j] = *reinterpret_cast<const bf16x8*>(reinterpret_cast<const char*>(T) + byteoff);
        }
        #pragma unroll
        for (int m = 0; m < 4; ++m)
            #pragma unroll
            for (int j = 0; j < 4; ++j)
                acc[m][j] = __builtin_amdgcn_mfma_f32_16x16x32_bf16(a[m], bf[j], acc[m][j], 0, 0, 0);
    }
    __syncthreads();    // everyone done reading X^T

    // epilogue 1: BN + ReLU -> bf16 -> Y^T[n][o] (same LDS buffer)
    #pragma unroll
    for (int m = 0; m < 4; ++m) {
        const int o0 = wo * 64 + m * 16 + kg * 4;
        const float4 s4 = *reinterpret_cast<const float4*>(sc1 + o0);
        const float4 h4 = *reinterpret_cast<const float4*>(sh1 + o0);
        #pragma unroll
        for (int j = 0; j < 4; ++j) {
            const int nn = wn * 64 + j * 16 + r16;
            float v0 = fmaxf(acc[m][j][0] * s4.x + h4.x, 0.0f);
            float v1 = fmaxf(acc[m][j][1] * s4.y + h4.y, 0.0f);
            float v2 = fmaxf(acc[m][j][2] * s4.z + h4.z, 0.0f);
            float v3 = fmaxf(acc[m][j][3] * s4.w + h4.w, 0.0f);
            u32x2 pk;
            pk[0] = (unsigned)f2bf(v0) | ((unsigned)f2bf(v1) << 16);
            pk[1] = (unsigned)f2bf(v2) | ((unsigned)f2bf(v3) << 16);
            const int byteoff = nn * 512 + ((o0 * 2) ^ ((nn & 7) << 4));
            *reinterpret_cast<u32x2*>(reinterpret_cast<char*>(T) + byteoff) = pk;
        }
    }
    __syncthreads();

    // ---------------- GEMM2: [128 o2] x [k=256] x [128 n] ----------------
    f32x4 acc2[2][4] = {};
    for (int ks = 0; ks < 8; ++ks) {
        const int kk = ks * 32;
        bf16x8 a[2], bf[4];
        #pragma unroll
        for (int m = 0; m < 2; ++m) {
            const int o = wo * 32 + m * 16 + r16;
            a[m] = *reinterpret_cast<const bf16x8*>(W2b + (size_t)o * O1C + kk + kg * 8);
        }
        #pragma unroll
        for (int j = 0; j < 4; ++j) {
            const int nn = wn * 64 + j * 16 + r16;
            const int byteoff = nn * 512 + (((kk + kg * 8) * 2) ^ ((nn & 7) << 4));
            bf[j] = *reinterpret_cast<const bf16x8*>(reinterpret_cast<const char*>(T) + byteoff);
        }
        #pragma unroll
        for (int m = 0; m < 2; ++m)
            #pragma unroll
            for (int j = 0; j < 4; ++j)
                acc2[m][j] = __builtin_amdgcn_mfma_f32_16x16x32_bf16(a[m], bf[j], acc2[m][j], 0, 0, 0);
    }

    // epilogue 2: BN + ReLU -> fp32 global store
    #pragma unroll
    for (int m = 0; m < 2; ++m) {
        const int o0 = wo * 32 + m * 16 + kg * 4;
        const float4 s4 = *reinterpret_cast<const float4*>(sc2 + o0);
        const float4 h4 = *reinterpret_cast<const float4*>(sh2 + o0);
        #pragma unroll
        for (int j = 0; j < 4; ++j) {
            const int nn = wn * 64 + j * 16 + r16;
            const size_t obase = ((size_t)b * O2C + o0) * NN + n0 + nn;
            out[obase]            = fmaxf(acc2[m][j][0] * s4.x + h4.x, 0.0f);
            out[obase + NN]       = fmaxf(acc2[m][j][1] * s4.y + h4.y, 0.0f);
            out[obase + 2 * NN]   = fmaxf(acc2[m][j][2] * s4.z + h4.z, 0.0f);
            out[obase + 3 * NN]   = fmaxf(acc2[m][j][3] * s4.w + h4.w, 0.0f);
        }
    }
}

// ---------------------------------------------------------------------------
extern "C" void kernel_launch(void* const* d_in, const int* in_sizes, int n_in,
                              void* d_out, int out_size, void* d_ws, size_t ws_size,
                              hipStream_t stream) {
    const float* xyz1    = (const float*)d_in[0];
    const float* xyz2    = (const float*)d_in[1];
    const float* points1 = (const float*)d_in[2];
    const float* points2 = (const float*)d_in[3];
    const float* W1  = (const float*)d_in[4];
    const float* b1  = (const float*)d_in[5];
    const float* g1  = (const float*)d_in[6];
    const float* be1 = (const float*)d_in[7];
    const float* m1  = (const float*)d_in[8];
    const float* v1  = (const float*)d_in[9];
    const float* W2  = (const float*)d_in[10];
    const float* b2  = (const float*)d_in[11];
    const float* g2  = (const float*)d_in[12];
    const float* be2 = (const float*)d_in[13];
    const float* m2  = (const float*)d_in[14];
    const float* v2  = (const float*)d_in[15];

    float* out = (float*)d_out;

    // workspace layout
    char* ws = (char*)d_ws;
    int*            ws_idx = (int*)ws;                                   // 786432 B
    float*          ws_w   = (float*)(ws + 786432);                      // 786432 B
    unsigned short* W1b    = (unsigned short*)(ws + 1572864);            // 131072 B
    unsigned short* W2b    = (unsigned short*)(ws + 1703936);            //  65536 B
    float*          sc1    = (float*)(ws + 1769472);                     //   1024 B
    float*          sh1    = (float*)(ws + 1770496);
    float*          sc2    = (float*)(ws + 1771520);                     //    512 B
    float*          sh2    = (float*)(ws + 1772032);
    float*          p2t    = (float*)(ws + 2097152);                     // 16 MB [B,S,D]

    prep_kernel<<<dim3(384), dim3(256), 0, stream>>>(
        W1, W2, b1, g1, be1, m1, v1, b2, g2, be2, m2, v2,
        W1b, W2b, sc1, sh1, sc2, sh2);

    transpose_kernel<<<dim3(BB * 64), dim3(256), 0, stream>>>(points2, p2t);

    knn3_kernel<<<dim3(BB * (NN / 64)), dim3(512), 0, stream>>>(
        xyz1, xyz2, ws_idx, ws_w);

    fused_mfma_kernel<<<dim3(BB * (NN / NT)), dim3(512), 0, stream>>>(
        points1, p2t, ws_idx, ws_w,
        W1b, W2b, sc1, sh1, sc2, sh2, out);
}

// Round 11
// 259.351 us; speedup vs baseline: 1.0672x; 1.0672x over previous
//
#include <hip/hip_runtime.h>
#include <hip/hip_bf16.h>

#define BB 16
#define NN 4096
#define SS 1024
#define DD 256
#define O1C 256
#define O2C 128
#define NT 64    // n-tile of fused kernel (32 KB LDS -> 4 blocks/CU)

typedef __attribute__((ext_vector_type(8))) short bf16x8;
typedef __attribute__((ext_vector_type(4))) float f32x4;
typedef __attribute__((ext_vector_type(2))) unsigned int u32x2;

static __device__ __forceinline__ unsigned short f2bf(float f) {
    union { float f; unsigned u; } v; v.f = f;
    unsigned r = (v.u + 0x7fffu + ((v.u >> 16) & 1u)) >> 16;
    return (unsigned short)r;
}

// ---------------------------------------------------------------------------
// Prep: W fp32 -> bf16, fold BN into scale/shift.  grid 384 x 256.
// ---------------------------------------------------------------------------
__global__ __launch_bounds__(256) void prep_kernel(
    const float* __restrict__ W1, const float* __restrict__ W2,
    const float* __restrict__ b1, const float* __restrict__ g1,
    const float* __restrict__ be1, const float* __restrict__ m1,
    const float* __restrict__ v1,
    const float* __restrict__ b2, const float* __restrict__ g2,
    const float* __restrict__ be2, const float* __restrict__ m2,
    const float* __restrict__ v2,
    unsigned short* __restrict__ W1b, unsigned short* __restrict__ W2b,
    float* __restrict__ sc1, float* __restrict__ sh1,
    float* __restrict__ sc2, float* __restrict__ sh2)
{
    int t = blockIdx.x * 256 + threadIdx.x;
    if (t < O1C * DD) W1b[t] = f2bf(W1[t]);
    int t2 = t - O1C * DD;
    if (t2 >= 0 && t2 < O2C * O1C) W2b[t2] = f2bf(W2[t2]);
    if (t < O1C) {
        float s = g1[t] / sqrtf(v1[t] + 1e-5f);
        sc1[t] = s;
        sh1[t] = (b1[t] - m1[t]) * s + be1[t];
    }
    if (t2 >= 0 && t2 < O2C) {
        float s = g2[t2] / sqrtf(v2[t2] + 1e-5f);
        sc2[t2] = s;
        sh2[t2] = (b2[t2] - m2[t2]) * s + be2[t2];
    }
}

// ---------------------------------------------------------------------------
// Transpose points2 [B,D,S] -> p2t [B,S,D] fp32.  64x64 tiles, padded LDS.
// grid: BB * 4 * 16 = 1024 blocks x 256 threads.
// ---------------------------------------------------------------------------
__global__ __launch_bounds__(256) void transpose_kernel(
    const float* __restrict__ p2,   // [B,D,S]
    float* __restrict__ p2t)        // [B,S,D]
{
    __shared__ float tile[64][65];
    const int b  = blockIdx.x >> 6;
    const int ct = (blockIdx.x >> 4) & 3;   // c-tile 0..3
    const int st = blockIdx.x & 15;         // s-tile 0..15
    const int c0 = ct * 64, s0 = st * 64;
    const int cl = threadIdx.x >> 6;        // 0..3
    const int sl = threadIdx.x & 63;

    const float* src = p2 + ((size_t)b * DD + c0) * SS + s0;
    #pragma unroll
    for (int r = 0; r < 16; ++r) {
        const int c = r * 4 + cl;
        tile[c][sl] = src[(size_t)c * SS + sl];
    }
    __syncthreads();
    float* dst = p2t + ((size_t)b * SS + s0) * DD + c0;
    #pragma unroll
    for (int r = 0; r < 16; ++r) {
        const int s = r * 4 + cl;
        dst[(size_t)s * DD + sl] = tile[sl][s];
    }
}

// ---------------------------------------------------------------------------
// knn3: 8 threads per point, each scans S/8 = 128, stable LDS merge.
// grid: BB * (NN/64) = 1024 blocks x 512 threads.
// ---------------------------------------------------------------------------
__global__ __launch_bounds__(512) void knn3_kernel(
    const float* __restrict__ xyz1,   // [B,3,N]
    const float* __restrict__ xyz2,   // [B,3,S]
    int* __restrict__ idx_out,        // [B,N,3]
    float* __restrict__ w_out)        // [B,N,3]
{
    __shared__ float4 q[SS];          // 16 KB
    __shared__ float  cd[512][3];     // 6 KB
    __shared__ int    ci[512][3];     // 6 KB

    const int b    = blockIdx.x >> 6;     // 64 tiles per batch
    const int tile = blockIdx.x & 63;
    const int p    = threadIdx.x & 63;
    const int seg  = threadIdx.x >> 6;    // 0..7: which eighth of S
    const int n    = tile * 64 + p;

    const float* x2 = xyz2 + (size_t)b * 3 * SS;
    for (int s = threadIdx.x; s < SS; s += 512) {
        float xx = x2[s], yy = x2[SS + s], zz = x2[2 * SS + s];
        q[s] = make_float4(xx, yy, zz, xx * xx + yy * yy + zz * zz);
    }
    __syncthreads();

    const float* x1 = xyz1 + (size_t)b * 3 * NN;
    const float px = x1[n], py = x1[NN + n], pz = x1[2 * NN + n];
    const float pn = px * px + py * py + pz * pz;

    const float FINF = 3.402823466e+38f;
    float d0 = FINF, d1 = FINF, d2 = FINF;
    int   i0 = 0,    i1 = 0,    i2 = 0;

    const int s0 = seg * (SS / 8);
    #pragma unroll 4
    for (int s = s0; s < s0 + SS / 8; ++s) {
        float4 v = q[s];
        float d = pn + v.w - 2.0f * (px * v.x + py * v.y + pz * v.z);
        if (d < d2) {
            if (d < d1) {
                if (d < d0) { d2 = d1; i2 = i1; d1 = d0; i1 = i0; d0 = d; i0 = s; }
                else        { d2 = d1; i2 = i1; d1 = d;  i1 = s; }
            } else          { d2 = d;  i2 = s; }
        }
    }
    cd[threadIdx.x][0] = d0; cd[threadIdx.x][1] = d1; cd[threadIdx.x][2] = d2;
    ci[threadIdx.x][0] = i0; ci[threadIdx.x][1] = i1; ci[threadIdx.x][2] = i2;
    __syncthreads();

    if (threadIdx.x < 64) {
        float m0 = cd[p][0], m1v = cd[p][1], m2v = cd[p][2];
        int   j0 = ci[p][0], j1 = ci[p][1], j2 = ci[p][2];
        #pragma unroll
        for (int qq = 1; qq < 8; ++qq) {
            const int t = qq * 64 + p;
            #pragma unroll
            for (int c = 0; c < 3; ++c) {
                float d = cd[t][c]; int i = ci[t][c];
                // strict < keeps earliest index on ties (top_k stability);
                // segments merged in ascending-s order
                if (d < m2v) {
                    if (d < m1v) {
                        if (d < m0) { m2v = m1v; j2 = j1; m1v = m0; j1 = j0; m0 = d; j0 = i; }
                        else        { m2v = m1v; j2 = j1; m1v = d;  j1 = i; }
                    } else          { m2v = d;  j2 = i; }
                }
            }
        }
        float r0 = 1.0f / (m0 + 1e-8f);
        float r1 = 1.0f / (m1v + 1e-8f);
        float r2 = 1.0f / (m2v + 1e-8f);
        float rs = 1.0f / (r0 + r1 + r2);
        size_t base = ((size_t)b * NN + n) * 3;
        idx_out[base + 0] = j0;
        idx_out[base + 1] = j1;
        idx_out[base + 2] = j2;
        w_out[base + 0] = r0 * rs;
        w_out[base + 1] = r1 * rs;
        w_out[base + 2] = r2 * rs;
    }
}

// ---------------------------------------------------------------------------
// Fused interp + MFMA MLP.  NT=64 retile for occupancy:
//   grid BB*(NN/64) = 1024 logical blocks x 256 threads (4 waves).
//   LDS T = 64 rows x 512 B = 32 KB -> 4 blocks/CU, 16 waves/CU target.
//   Per-wave work identical to Round-7 kernel (16-point staging, acc[4][4],
//   acc2[2][4], same K order) -> bit-identical accumulation.
//   XCD swizzle: lb = (bid%8)*128 + bid/8 -> each XCD owns 2 whole batches,
//   p2t working set 2 MB < 4 MB L2.
// ---------------------------------------------------------------------------
__global__ __launch_bounds__(256) void fused_mfma_kernel(
    const float* __restrict__ points1,  // [B,D,N]
    const float* __restrict__ p2t,      // [B,S,D] fp32
    const int*   __restrict__ idx_in,   // [B,N,3]
    const float* __restrict__ w_in,     // [B,N,3]
    const unsigned short* __restrict__ W1b,  // [O1,D] bf16
    const unsigned short* __restrict__ W2b,  // [O2,O1] bf16
    const float* __restrict__ sc1, const float* __restrict__ sh1,
    const float* __restrict__ sc2, const float* __restrict__ sh2,
    float* __restrict__ out)            // [B,O2,N]
{
    __shared__ unsigned short T[NT * DD];   // 32 KB

    const int lb   = ((blockIdx.x & 7) << 7) + (blockIdx.x >> 3);  // bijective, 1024%8==0
    const int b    = lb >> 6;             // 64 tiles per batch
    const int n0   = (lb & 63) << 6;
    const int tid  = threadIdx.x;
    const int lane = tid & 63;
    const int w    = tid >> 6;            // wave 0..3

    // ---------------- stage X^T[p][c] via coalesced row gather ----------------
    {
        const float* p2tb = p2t + (size_t)b * SS * DD;
        const float* p1b  = points1 + (size_t)b * DD * NN;
        #pragma unroll 2
        for (int pp = 0; pp < 16; ++pp) {
            const int p = w * 16 + pp;
            const int n = n0 + p;
            const size_t ibase = ((size_t)b * NN + n) * 3;
            const int   gi0 = idx_in[ibase + 0];
            const int   gi1 = idx_in[ibase + 1];
            const int   gi2 = idx_in[ibase + 2];
            const float gw0 = w_in[ibase + 0];
            const float gw1 = w_in[ibase + 1];
            const float gw2 = w_in[ibase + 2];
            const float4 r0 = *reinterpret_cast<const float4*>(p2tb + (size_t)gi0 * DD + 4 * lane);
            const float4 r1 = *reinterpret_cast<const float4*>(p2tb + (size_t)gi1 * DD + 4 * lane);
            const float4 r2 = *reinterpret_cast<const float4*>(p2tb + (size_t)gi2 * DD + 4 * lane);
            const float x0 = p1b[(size_t)(4 * lane + 0) * NN + n] + gw0 * r0.x + gw1 * r1.x + gw2 * r2.x;
            const float x1 = p1b[(size_t)(4 * lane + 1) * NN + n] + gw0 * r0.y + gw1 * r1.y + gw2 * r2.y;
            const float x2 = p1b[(size_t)(4 * lane + 2) * NN + n] + gw0 * r0.z + gw1 * r1.z + gw2 * r2.z;
            const float x3 = p1b[(size_t)(4 * lane + 3) * NN + n] + gw0 * r0.w + gw1 * r1.w + gw2 * r2.w;
            u32x2 pk;
            pk[0] = (unsigned)f2bf(x0) | ((unsigned)f2bf(x1) << 16);
            pk[1] = (unsigned)f2bf(x2) | ((unsigned)f2bf(x3) << 16);
            const int byteoff = p * 512 + ((8 * lane) ^ ((p & 7) << 4));
            *reinterpret_cast<u32x2*>(reinterpret_cast<char*>(T) + byteoff) = pk;
        }
    }
    __syncthreads();

    const int r16 = lane & 15;
    const int kg  = lane >> 4;

    // ---------------- GEMM1: [256 o] x [k=256] x [64 n] ----------------
    f32x4 acc[4][4] = {};
    for (int ks = 0; ks < 8; ++ks) {
        const int kk = ks * 32;
        bf16x8 a[4], bf[4];
        #pragma unroll
        for (int m = 0; m < 4; ++m) {
            const int o = w * 64 + m * 16 + r16;
            a[m] = *reinterpret_cast<const bf16x8*>(W1b + (size_t)o * DD + kk + kg * 8);
        }
        #pragma unroll
        for (int j = 0; j < 4; ++j) {
            const int nn = j * 16 + r16;
            const int byteoff = nn * 512 + (((kk + kg * 8) * 2) ^ ((nn & 7) << 4));
            bf[j] = *reinterpret_cast<const bf16x8*>(reinterpret_cast<const char*>(T) + byteoff);
        }
        #pragma unroll
        for (int m = 0; m < 4; ++m)
            #pragma unroll
            for (int j = 0; j < 4; ++j)
                acc[m][j] = __builtin_amdgcn_mfma_f32_16x16x32_bf16(a[m], bf[j], acc[m][j], 0, 0, 0);
    }
    __syncthreads();    // everyone done reading X^T

    // epilogue 1: BN + ReLU -> bf16 -> Y^T[n][o] (same LDS buffer)
    #pragma unroll
    for (int m = 0; m < 4; ++m) {
        const int o0 = w * 64 + m * 16 + kg * 4;
        const float4 s4 = *reinterpret_cast<const float4*>(sc1 + o0);
        const float4 h4 = *reinterpret_cast<const float4*>(sh1 + o0);
        #pragma unroll
        for (int j = 0; j < 4; ++j) {
            const int nn = j * 16 + r16;
            float v0 = fmaxf(acc[m][j][0] * s4.x + h4.x, 0.0f);
            float v1 = fmaxf(acc[m][j][1] * s4.y + h4.y, 0.0f);
            float v2 = fmaxf(acc[m][j][2] * s4.z + h4.z, 0.0f);
            float v3 = fmaxf(acc[m][j][3] * s4.w + h4.w, 0.0f);
            u32x2 pk;
            pk[0] = (unsigned)f2bf(v0) | ((unsigned)f2bf(v1) << 16);
            pk[1] = (unsigned)f2bf(v2) | ((unsigned)f2bf(v3) << 16);
            const int byteoff = nn * 512 + ((o0 * 2) ^ ((nn & 7) << 4));
            *reinterpret_cast<u32x2*>(reinterpret_cast<char*>(T) + byteoff) = pk;
        }
    }
    __syncthreads();

    // ---------------- GEMM2: [128 o2] x [k=256] x [64 n] ----------------
    f32x4 acc2[2][4] = {};
    for (int ks = 0; ks < 8; ++ks) {
        const int kk = ks * 32;
        bf16x8 a[2], bf[4];
        #pragma unroll
        for (int m = 0; m < 2; ++m) {
            const int o = w * 32 + m * 16 + r16;
            a[m] = *reinterpret_cast<const bf16x8*>(W2b + (size_t)o * O1C + kk + kg * 8);
        }
        #pragma unroll
        for (int j = 0; j < 4; ++j) {
            const int nn = j * 16 + r16;
            const int byteoff = nn * 512 + (((kk + kg * 8) * 2) ^ ((nn & 7) << 4));
            bf[j] = *reinterpret_cast<const bf16x8*>(reinterpret_cast<const char*>(T) + byteoff);
        }
        #pragma unroll
        for (int m = 0; m < 2; ++m)
            #pragma unroll
            for (int j = 0; j < 4; ++j)
                acc2[m][j] = __builtin_amdgcn_mfma_f32_16x16x32_bf16(a[m], bf[j], acc2[m][j], 0, 0, 0);
    }

    // epilogue 2: BN + ReLU -> fp32 global store
    #pragma unroll
    for (int m = 0; m < 2; ++m) {
        const int o0 = w * 32 + m * 16 + kg * 4;
        const float4 s4 = *reinterpret_cast<const float4*>(sc2 + o0);
        const float4 h4 = *reinterpret_cast<const float4*>(sh2 + o0);
        #pragma unroll
        for (int j = 0; j < 4; ++j) {
            const int nn = j * 16 + r16;
            const size_t obase = ((size_t)b * O2C + o0) * NN + n0 + nn;
            out[obase]            = fmaxf(acc2[m][j][0] * s4.x + h4.x, 0.0f);
            out[obase + NN]       = fmaxf(acc2[m][j][1] * s4.y + h4.y, 0.0f);
            out[obase + 2 * NN]   = fmaxf(acc2[m][j][2] * s4.z + h4.z, 0.0f);
            out[obase + 3 * NN]   = fmaxf(acc2[m][j][3] * s4.w + h4.w, 0.0f);
        }
    }
}

// ---------------------------------------------------------------------------
extern "C" void kernel_launch(void* const* d_in, const int* in_sizes, int n_in,
                              void* d_out, int out_size, void* d_ws, size_t ws_size,
                              hipStream_t stream) {
    const float* xyz1    = (const float*)d_in[0];
    const float* xyz2    = (const float*)d_in[1];
    const float* points1 = (const float*)d_in[2];
    const float* points2 = (const float*)d_in[3];
    const float* W1  = (const float*)d_in[4];
    const float* b1  = (const float*)d_in[5];
    const float* g1  = (const float*)d_in[6];
    const float* be1 = (const float*)d_in[7];
    const float* m1  = (const float*)d_in[8];
    const float* v1  = (const float*)d_in[9];
    const float* W2  = (const float*)d_in[10];
    const float* b2  = (const float*)d_in[11];
    const float* g2  = (const float*)d_in[12];
    const float* be2 = (const float*)d_in[13];
    const float* m2  = (const float*)d_in[14];
    const float* v2  = (const float*)d_in[15];

    float* out = (float*)d_out;

    // workspace layout
    char* ws = (char*)d_ws;
    int*            ws_idx = (int*)ws;                                   // 786432 B
    float*          ws_w   = (float*)(ws + 786432);                      // 786432 B
    unsigned short* W1b    = (unsigned short*)(ws + 1572864);            // 131072 B
    unsigned short* W2b    = (unsigned short*)(ws + 1703936);            //  65536 B
    float*          sc1    = (float*)(ws + 1769472);                     //   1024 B
    float*          sh1    = (float*)(ws + 1770496);
    float*          sc2    = (float*)(ws + 1771520);                     //    512 B
    float*          sh2    = (float*)(ws + 1772032);
    float*          p2t    = (float*)(ws + 2097152);                     // 16 MB [B,S,D]

    prep_kernel<<<dim3(384), dim3(256), 0, stream>>>(
        W1, W2, b1, g1, be1, m1, v1, b2, g2, be2, m2, v2,
        W1b, W2b, sc1, sh1, sc2, sh2);

    transpose_kernel<<<dim3(BB * 64), dim3(256), 0, stream>>>(points2, p2t);

    knn3_kernel<<<dim3(BB * (NN / 64)), dim3(512), 0, stream>>>(
        xyz1, xyz2, ws_idx, ws_w);

    fused_mfma_kernel<<<dim3(BB * (NN / NT)), dim3(256), 0, stream>>>(
        points1, p2t, ws_idx, ws_w,
        W1b, W2b, sc1, sh1, sc2, sh2, out);
}